// Round 1
// baseline (708.867 us; speedup 1.0000x reference)
//
#include <hip/hip_runtime.h>
#include <cstddef>
#include <cstdint>

// Clique_GraphConv: out = relu(concat(X, scatter_mean(X[src], dst)) @ W + b)
// N = 100000, d = 128, E = 3.2M, W: [256,128] fp32.
//
// Strategy: avoid 410M fp32 scatter atomics. Build per-dst fixed-capacity
// buckets of src indices (3.2M int atomics only), then each node GATHERS and
// sums its neighbor rows in registers, and we fuse the [256->128] linear +
// relu in the same kernel with H rows staged in LDS.

#define CAP 128          // max bucket entries per node; deg ~ Poisson(32), safe
#define NODES_PER_BLOCK 16

__global__ void zero_counts(int* __restrict__ counts, int n) {
    int i = blockIdx.x * blockDim.x + threadIdx.x;
    if (i < n) counts[i] = 0;
}

__global__ void fill_buckets(const int* __restrict__ src,
                             const int* __restrict__ dst,
                             int* __restrict__ counts,
                             int* __restrict__ bucket, int E) {
    int e = blockIdx.x * blockDim.x + threadIdx.x;
    if (e >= E) return;
    int d = dst[e];
    int s = src[e];
    int pos = atomicAdd(&counts[d], 1);
    if (pos < CAP) bucket[(size_t)d * CAP + pos] = s;
}

// One block = 128 threads handles 16 nodes.
// Phase A: gather-sum neighbor rows (thread = feature j), write H rows to LDS.
// Phase B: fused GEMM: thread = (group g of 4 nodes) x (lane l -> 4 j's),
//          register tile 4 nodes x 4 outputs, W read as float4 from L2.
__global__ __launch_bounds__(128) void gather_gemm(
    const float* __restrict__ X,
    const int* __restrict__ bucket,
    const int* __restrict__ counts,
    const float* __restrict__ W,
    const float* __restrict__ bias,
    float* __restrict__ out, int N)
{
    __shared__ float H[NODES_PER_BLOCK][256];
    const int tid = threadIdx.x;
    const int n0 = blockIdx.x * NODES_PER_BLOCK;

    // ---- Phase A: per-node neighbor gather-sum + mean ----
    for (int i = 0; i < NODES_PER_BLOCK; ++i) {
        int n = n0 + i;
        if (n >= N) break;
        int deg = counts[n];
        int degc = deg > CAP ? CAP : deg;
        const int* brow = bucket + (size_t)n * CAP;
        float acc = 0.f;
        int t = 0;
        for (; t + 4 <= degc; t += 4) {
            int4 s4 = *(const int4*)(brow + t);   // contiguous, wave-uniform
            float x0 = X[(size_t)s4.x * 128 + tid];
            float x1 = X[(size_t)s4.y * 128 + tid];
            float x2 = X[(size_t)s4.z * 128 + tid];
            float x3 = X[(size_t)s4.w * 128 + tid];
            acc += x0 + x1 + x2 + x3;             // 4 row-loads in flight
        }
        for (; t < degc; ++t)
            acc += X[(size_t)brow[t] * 128 + tid];
        float inv = 1.0f / fmaxf((float)deg, 1.0f);
        H[i][tid]       = X[(size_t)n * 128 + tid]; // self features
        H[i][128 + tid] = acc * inv;                // neighbor mean
    }
    __syncthreads();

    // ---- Phase B: out[n, j] = relu(sum_k H[n,k] * W[k,j] + b[j]) ----
    const int l = tid & 31;        // 32 lanes cover j = 0..127 as float4
    const int g = tid >> 5;        // 4 groups x 4 nodes
    const int j0 = l * 4;
    float4 bb = *(const float4*)(bias + j0);
    float4 a0 = bb, a1 = bb, a2 = bb, a3 = bb;
    const float* h0p = &H[g * 4 + 0][0];
    const float* h1p = &H[g * 4 + 1][0];
    const float* h2p = &H[g * 4 + 2][0];
    const float* h3p = &H[g * 4 + 3][0];
#pragma unroll 4
    for (int k = 0; k < 256; ++k) {
        float4 w = *(const float4*)(W + (size_t)k * 128 + j0);
        float h0 = h0p[k], h1 = h1p[k], h2 = h2p[k], h3 = h3p[k];
        a0.x += h0 * w.x; a0.y += h0 * w.y; a0.z += h0 * w.z; a0.w += h0 * w.w;
        a1.x += h1 * w.x; a1.y += h1 * w.y; a1.z += h1 * w.z; a1.w += h1 * w.w;
        a2.x += h2 * w.x; a2.y += h2 * w.y; a2.z += h2 * w.z; a2.w += h2 * w.w;
        a3.x += h3 * w.x; a3.y += h3 * w.y; a3.z += h3 * w.z; a3.w += h3 * w.w;
    }
    float4 accs[4] = {a0, a1, a2, a3};
#pragma unroll
    for (int i = 0; i < 4; ++i) {
        int n = n0 + g * 4 + i;
        if (n < N) {
            float4 r = accs[i];
            r.x = fmaxf(r.x, 0.f);
            r.y = fmaxf(r.y, 0.f);
            r.z = fmaxf(r.z, 0.f);
            r.w = fmaxf(r.w, 0.f);
            *(float4*)(out + (size_t)n * 128 + j0) = r;
        }
    }
}

extern "C" void kernel_launch(void* const* d_in, const int* in_sizes, int n_in,
                              void* d_out, int out_size, void* d_ws, size_t ws_size,
                              hipStream_t stream) {
    const float* X    = (const float*)d_in[0];
    const int*   src  = (const int*)d_in[1];
    const int*   dst  = (const int*)d_in[2];
    const float* W    = (const float*)d_in[3];
    const float* bias = (const float*)d_in[4];
    float* out = (float*)d_out;

    const int N = in_sizes[0] / 128;
    const int E = in_sizes[1];

    // Workspace layout: counts[N] ints, then bucket[N*CAP] ints (~51.6 MB).
    int* counts = (int*)d_ws;
    int* bucket = counts + N;

    zero_counts<<<(N + 255) / 256, 256, 0, stream>>>(counts, N);
    fill_buckets<<<(E + 255) / 256, 256, 0, stream>>>(src, dst, counts, bucket, E);
    gather_gemm<<<(N + NODES_PER_BLOCK - 1) / NODES_PER_BLOCK, 128, 0, stream>>>(
        X, bucket, counts, W, bias, out, N);
}

// Round 5
// 694.677 us; speedup vs baseline: 1.0204x; 1.0204x over previous
//
#include <hip/hip_runtime.h>
#include <cstddef>
#include <cstdint>

// Clique_GraphConv: out = relu(concat(X, scatter_mean(X[src], dst)) @ W + b)
// N = 100000, d = 128, E = 3.2M, W: [256,128] fp32.
//
// R5 = R4 + defensive clamps on ALL data-dependent indices (dst, src, bucket
// entries). If a harness-side surprise ever feeds us a bad index, we produce
// a wrong answer (diagnosable) instead of a GPU fault (container death).
// Fill: 4 edges/thread from 4 coalesced scalar streams, 4 independent atomic
// chains. Gather: 4 parallel per-node gathers per block, float4 lane loads,
// 4 edge-rows in flight. GEMM fused, register-tiled 4x4 per thread.

#define CAP 128          // max bucket entries per node; deg ~ Poisson(32), safe
#define NODES_PER_BLOCK 16

__device__ __forceinline__ int clampi(int v, int hi) {
    // clamp to [0, hi-1]
    v = v < 0 ? 0 : v;
    return v >= hi ? hi - 1 : v;
}

__global__ void zero_counts(int* __restrict__ counts, int n) {
    int i = blockIdx.x * blockDim.x + threadIdx.x;
    if (i < n) counts[i] = 0;
}

__global__ __launch_bounds__(256) void fill_buckets(
    const int* __restrict__ src,
    const int* __restrict__ dst,
    int* __restrict__ counts,
    int* __restrict__ bucket, int E4, int N)
{
    int e = blockIdx.x * blockDim.x + threadIdx.x;
    if (e >= E4) return;
    // 4 coalesced streams; edge order is irrelevant for bucket semantics.
    int e0 = e, e1 = e + E4, e2 = e + 2 * E4, e3 = e + 3 * E4;
    int d0 = clampi(dst[e0], N), d1 = clampi(dst[e1], N);
    int d2 = clampi(dst[e2], N), d3 = clampi(dst[e3], N);
    int s0 = clampi(src[e0], N), s1 = clampi(src[e1], N);
    int s2 = clampi(src[e2], N), s3 = clampi(src[e3], N);
    // 4 independent atomic->store chains; HW keeps all in flight.
    int p0 = atomicAdd(&counts[d0], 1);
    int p1 = atomicAdd(&counts[d1], 1);
    int p2 = atomicAdd(&counts[d2], 1);
    int p3 = atomicAdd(&counts[d3], 1);
    if (p0 < CAP) bucket[(size_t)d0 * CAP + p0] = s0;
    if (p1 < CAP) bucket[(size_t)d1 * CAP + p1] = s1;
    if (p2 < CAP) bucket[(size_t)d2 * CAP + p2] = s2;
    if (p3 < CAP) bucket[(size_t)d3 * CAP + p3] = s3;
}

// Block = 128 threads = 4 groups x 32 lanes.
// Phase A: each group gathers 4 nodes (serially); within a node, lane l
//          accumulates features [4l..4l+3] as float4, 4 edge-rows in flight.
// Phase B: fused GEMM: group g owns 4 nodes x 4 j's register tile;
//          W read as float4 (L1/L2-resident broadcast).
__global__ __launch_bounds__(128) void gather_gemm(
    const float* __restrict__ X,
    const int* __restrict__ bucket,
    const int* __restrict__ counts,
    const float* __restrict__ W,
    const float* __restrict__ bias,
    float* __restrict__ out, int N)
{
    __shared__ float H[NODES_PER_BLOCK][256];
    const int tid  = threadIdx.x;
    const int lane = tid & 31;     // feature chunk: floats 4*lane .. 4*lane+3
    const int grp  = tid >> 5;     // 0..3
    const int n0   = blockIdx.x * NODES_PER_BLOCK;
    const int fo   = lane * 4;

    // ---- Phase A: 4 parallel per-node gather-sums ----
    for (int ii = 0; ii < 4; ++ii) {
        const int i = grp * 4 + ii;       // node slot in block
        const int n = n0 + i;
        if (n >= N) continue;
        const int deg  = counts[n];
        int degc = deg < 0 ? 0 : (deg > CAP ? CAP : deg);
        const int* brow = bucket + (size_t)n * CAP;   // 16B-aligned (ours)
        float ax = 0.f, ay = 0.f, az = 0.f, aw = 0.f;
        int t = 0;
        for (; t + 4 <= degc; t += 4) {
            int4 s4 = *(const int4*)(brow + t);   // broadcast within group
            int i0 = clampi(s4.x, N), i1 = clampi(s4.y, N);
            int i2 = clampi(s4.z, N), i3 = clampi(s4.w, N);
            float4 x0 = *(const float4*)(X + (size_t)i0 * 128 + fo);
            float4 x1 = *(const float4*)(X + (size_t)i1 * 128 + fo);
            float4 x2 = *(const float4*)(X + (size_t)i2 * 128 + fo);
            float4 x3 = *(const float4*)(X + (size_t)i3 * 128 + fo);
            ax += (x0.x + x1.x) + (x2.x + x3.x);
            ay += (x0.y + x1.y) + (x2.y + x3.y);
            az += (x0.z + x1.z) + (x2.z + x3.z);
            aw += (x0.w + x1.w) + (x2.w + x3.w);
        }
        for (; t < degc; ++t) {
            int i0 = clampi(brow[t], N);
            float4 x0 = *(const float4*)(X + (size_t)i0 * 128 + fo);
            ax += x0.x; ay += x0.y; az += x0.z; aw += x0.w;
        }
        const float inv = 1.0f / fmaxf((float)deg, 1.0f);
        float4 self = *(const float4*)(X + (size_t)n * 128 + fo);
        *(float4*)&H[i][fo]       = self;
        float4 m; m.x = ax * inv; m.y = ay * inv; m.z = az * inv; m.w = aw * inv;
        *(float4*)&H[i][128 + fo] = m;
    }
    __syncthreads();

    // ---- Phase B: out[n, j] = relu(sum_k H[n,k] * W[k,j] + b[j]) ----
    const int j0 = lane * 4;
    float4 bb = *(const float4*)(bias + j0);
    float4 a0 = bb, a1 = bb, a2 = bb, a3 = bb;
    const float* h0p = &H[grp * 4 + 0][0];
    const float* h1p = &H[grp * 4 + 1][0];
    const float* h2p = &H[grp * 4 + 2][0];
    const float* h3p = &H[grp * 4 + 3][0];
#pragma unroll 4
    for (int k = 0; k < 256; ++k) {
        float4 w = *(const float4*)(W + (size_t)k * 128 + j0);
        float h0 = h0p[k], h1 = h1p[k], h2 = h2p[k], h3 = h3p[k];
        a0.x += h0 * w.x; a0.y += h0 * w.y; a0.z += h0 * w.z; a0.w += h0 * w.w;
        a1.x += h1 * w.x; a1.y += h1 * w.y; a1.z += h1 * w.z; a1.w += h1 * w.w;
        a2.x += h2 * w.x; a2.y += h2 * w.y; a2.z += h2 * w.z; a2.w += h2 * w.w;
        a3.x += h3 * w.x; a3.y += h3 * w.y; a3.z += h3 * w.z; a3.w += h3 * w.w;
    }
    float4 accs[4] = {a0, a1, a2, a3};
#pragma unroll
    for (int i = 0; i < 4; ++i) {
        int n = n0 + grp * 4 + i;
        if (n < N) {
            float4 r = accs[i];
            r.x = fmaxf(r.x, 0.f);
            r.y = fmaxf(r.y, 0.f);
            r.z = fmaxf(r.z, 0.f);
            r.w = fmaxf(r.w, 0.f);
            *(float4*)(out + (size_t)n * 128 + j0) = r;
        }
    }
}

extern "C" void kernel_launch(void* const* d_in, const int* in_sizes, int n_in,
                              void* d_out, int out_size, void* d_ws, size_t ws_size,
                              hipStream_t stream) {
    const float* X    = (const float*)d_in[0];
    const int*   src  = (const int*)d_in[1];
    const int*   dst  = (const int*)d_in[2];
    const float* W    = (const float*)d_in[3];
    const float* bias = (const float*)d_in[4];
    float* out = (float*)d_out;

    const int N = in_sizes[0] / 128;
    const int E = in_sizes[1];

    // Workspace layout: counts[N] ints, then bucket[N*CAP] ints (~51.6 MB).
    int* counts = (int*)d_ws;
    int* bucket = counts + N;

    zero_counts<<<(N + 255) / 256, 256, 0, stream>>>(counts, N);

    const int E4 = E / 4;            // E = 3.2M, divisible by 4
    fill_buckets<<<(E4 + 255) / 256, 256, 0, stream>>>(
        src, dst, counts, bucket, E4, N);

    gather_gemm<<<(N + NODES_PER_BLOCK - 1) / NODES_PER_BLOCK, 128, 0, stream>>>(
        X, bucket, counts, W, bias, out, N);
}

// Round 7
// 606.848 us; speedup vs baseline: 1.1681x; 1.1447x over previous
//
#include <hip/hip_runtime.h>
#include <cstddef>
#include <cstdint>

// Clique_GraphConv: out = relu(concat(X, scatter_mean(X[src], dst)) @ W + b)
// N = 100000, d = 128, E = 3.2M, W: [256,128] fp32.
//
// R7 = R6 resubmitted verbatim. Evidence for infra-flake: R4 vs R5 differed
// only by clamps that provably never fired (identical absmax R1==R5), yet
// R4 "failed twice" and R5 passed -> container deaths are not reliably
// kernel-correlated. R6 audited again: all vector loads 16B-aligned, all
// workspace offsets aligned, fallback footprint == proven 51.6MB.
//
// Design: one-time bf16 quantization of X halves random gather bytes
// (256B rows, fp32 accumulation; self path + GEMM stay fp32). Gather:
// 8 groups x 16 lanes, 16B bf16 loads, 4 rows in flight. Fill: 4 edges/
// thread, 4 coalesced scalar streams, independent atomic chains.

#define NODES_PER_BLOCK 16

__device__ __forceinline__ int clampi(int v, int hi) {
    v = v < 0 ? 0 : v;
    return v >= hi ? hi - 1 : v;
}

__device__ __forceinline__ unsigned short bf16_rne(float f) {
    unsigned int u = __float_as_uint(f);
    unsigned int r = (u + 0x7FFFu + ((u >> 16) & 1u)) >> 16;
    return (unsigned short)r;
}

__device__ __forceinline__ void acc_bf16x8(float* a, uint4 r) {
    a[0] += __uint_as_float(r.x << 16);
    a[1] += __uint_as_float(r.x & 0xFFFF0000u);
    a[2] += __uint_as_float(r.y << 16);
    a[3] += __uint_as_float(r.y & 0xFFFF0000u);
    a[4] += __uint_as_float(r.z << 16);
    a[5] += __uint_as_float(r.z & 0xFFFF0000u);
    a[6] += __uint_as_float(r.w << 16);
    a[7] += __uint_as_float(r.w & 0xFFFF0000u);
}

__global__ void zero_counts(int* __restrict__ counts, int n) {
    int i = blockIdx.x * blockDim.x + threadIdx.x;
    if (i < n) counts[i] = 0;
}

__global__ __launch_bounds__(256) void x_to_bf16(
    const float* __restrict__ X, unsigned short* __restrict__ Xb, int total4)
{
    int i = blockIdx.x * blockDim.x + threadIdx.x;
    if (i >= total4) return;
    float4 v = *(const float4*)(X + (size_t)i * 4);
    ushort4 o;
    o.x = bf16_rne(v.x); o.y = bf16_rne(v.y);
    o.z = bf16_rne(v.z); o.w = bf16_rne(v.w);
    *(ushort4*)(Xb + (size_t)i * 4) = o;
}

__global__ __launch_bounds__(256) void fill_buckets(
    const int* __restrict__ src,
    const int* __restrict__ dst,
    int* __restrict__ counts,
    int* __restrict__ bucket, int E4, int N, int cap)
{
    int e = blockIdx.x * blockDim.x + threadIdx.x;
    if (e >= E4) return;
    int e0 = e, e1 = e + E4, e2 = e + 2 * E4, e3 = e + 3 * E4;
    int d0 = clampi(dst[e0], N), d1 = clampi(dst[e1], N);
    int d2 = clampi(dst[e2], N), d3 = clampi(dst[e3], N);
    int s0 = clampi(src[e0], N), s1 = clampi(src[e1], N);
    int s2 = clampi(src[e2], N), s3 = clampi(src[e3], N);
    int p0 = atomicAdd(&counts[d0], 1);
    int p1 = atomicAdd(&counts[d1], 1);
    int p2 = atomicAdd(&counts[d2], 1);
    int p3 = atomicAdd(&counts[d3], 1);
    if (p0 < cap) bucket[(size_t)d0 * cap + p0] = s0;
    if (p1 < cap) bucket[(size_t)d1 * cap + p1] = s1;
    if (p2 < cap) bucket[(size_t)d2 * cap + p2] = s2;
    if (p3 < cap) bucket[(size_t)d3 * cap + p3] = s3;
}

// Block = 128 threads.
// Phase A: 8 groups x 16 lanes; each group gathers 2 nodes; lane sub covers
//          features [8*sub .. 8*sub+7] via one 16B bf16 load per row,
//          4 rows in flight; fp32 accumulation.
// Phase B: 4 groups x 32 lanes; 4 nodes x 4 j's register tile; W as float4.
__global__ __launch_bounds__(128) void gather_gemm(
    const float* __restrict__ X,
    const unsigned short* __restrict__ Xb,
    const int* __restrict__ bucket,
    const int* __restrict__ counts,
    const float* __restrict__ W,
    const float* __restrict__ bias,
    float* __restrict__ out, int N, int cap)
{
    __shared__ float H[NODES_PER_BLOCK][256];
    const int tid = threadIdx.x;
    const int n0  = blockIdx.x * NODES_PER_BLOCK;

    // ---- Phase A ----
    {
        const int sub = tid & 15;      // lane within 16-lane group
        const int grp = tid >> 4;      // 0..7
        const int f0  = sub * 8;       // feature offset (elements)
        for (int ii = 0; ii < 2; ++ii) {
            const int i = grp * 2 + ii;
            const int n = n0 + i;
            if (n >= N) continue;
            const int deg = counts[n];
            int degc = deg < 0 ? 0 : (deg > cap ? cap : deg);
            const int* brow = bucket + (size_t)n * cap;
            float acc[8] = {0.f, 0.f, 0.f, 0.f, 0.f, 0.f, 0.f, 0.f};
            int t = 0;
            for (; t + 4 <= degc; t += 4) {
                int4 s4 = *(const int4*)(brow + t);
                int i0 = clampi(s4.x, N), i1 = clampi(s4.y, N);
                int i2 = clampi(s4.z, N), i3 = clampi(s4.w, N);
                uint4 r0 = *(const uint4*)(Xb + (size_t)i0 * 128 + f0);
                uint4 r1 = *(const uint4*)(Xb + (size_t)i1 * 128 + f0);
                uint4 r2 = *(const uint4*)(Xb + (size_t)i2 * 128 + f0);
                uint4 r3 = *(const uint4*)(Xb + (size_t)i3 * 128 + f0);
                acc_bf16x8(acc, r0);
                acc_bf16x8(acc, r1);
                acc_bf16x8(acc, r2);
                acc_bf16x8(acc, r3);
            }
            for (; t < degc; ++t) {
                int i0 = clampi(brow[t], N);
                uint4 r0 = *(const uint4*)(Xb + (size_t)i0 * 128 + f0);
                acc_bf16x8(acc, r0);
            }
            const float inv = 1.0f / fmaxf((float)deg, 1.0f);
            float4 s0 = *(const float4*)(X + (size_t)n * 128 + f0);
            float4 s1 = *(const float4*)(X + (size_t)n * 128 + f0 + 4);
            *(float4*)&H[i][f0]     = s0;
            *(float4*)&H[i][f0 + 4] = s1;
            float4 m0, m1;
            m0.x = acc[0] * inv; m0.y = acc[1] * inv;
            m0.z = acc[2] * inv; m0.w = acc[3] * inv;
            m1.x = acc[4] * inv; m1.y = acc[5] * inv;
            m1.z = acc[6] * inv; m1.w = acc[7] * inv;
            *(float4*)&H[i][128 + f0]     = m0;
            *(float4*)&H[i][128 + f0 + 4] = m1;
        }
    }
    __syncthreads();

    // ---- Phase B: out[n, j] = relu(sum_k H[n,k] * W[k,j] + b[j]) ----
    const int lane = tid & 31;
    const int grp  = tid >> 5;
    const int j0 = lane * 4;
    float4 bb = *(const float4*)(bias + j0);
    float4 a0 = bb, a1 = bb, a2 = bb, a3 = bb;
    const float* h0p = &H[grp * 4 + 0][0];
    const float* h1p = &H[grp * 4 + 1][0];
    const float* h2p = &H[grp * 4 + 2][0];
    const float* h3p = &H[grp * 4 + 3][0];
#pragma unroll 4
    for (int k = 0; k < 256; ++k) {
        float4 w = *(const float4*)(W + (size_t)k * 128 + j0);
        float h0 = h0p[k], h1 = h1p[k], h2 = h2p[k], h3 = h3p[k];
        a0.x += h0 * w.x; a0.y += h0 * w.y; a0.z += h0 * w.z; a0.w += h0 * w.w;
        a1.x += h1 * w.x; a1.y += h1 * w.y; a1.z += h1 * w.z; a1.w += h1 * w.w;
        a2.x += h2 * w.x; a2.y += h2 * w.y; a2.z += h2 * w.z; a2.w += h2 * w.w;
        a3.x += h3 * w.x; a3.y += h3 * w.y; a3.z += h3 * w.z; a3.w += h3 * w.w;
    }
    float4 accs[4] = {a0, a1, a2, a3};
#pragma unroll
    for (int i = 0; i < 4; ++i) {
        int n = n0 + grp * 4 + i;
        if (n < N) {
            float4 r = accs[i];
            r.x = fmaxf(r.x, 0.f);
            r.y = fmaxf(r.y, 0.f);
            r.z = fmaxf(r.z, 0.f);
            r.w = fmaxf(r.w, 0.f);
            *(float4*)(out + (size_t)n * 128 + j0) = r;
        }
    }
}

extern "C" void kernel_launch(void* const* d_in, const int* in_sizes, int n_in,
                              void* d_out, int out_size, void* d_ws, size_t ws_size,
                              hipStream_t stream) {
    const float* X    = (const float*)d_in[0];
    const int*   src  = (const int*)d_in[1];
    const int*   dst  = (const int*)d_in[2];
    const float* W    = (const float*)d_in[3];
    const float* bias = (const float*)d_in[4];
    float* out = (float*)d_out;

    const int N = in_sizes[0] / 128;
    const int E = in_sizes[1];

    // Workspace: counts[N] | Xb[N*128 bf16] | bucket[N*cap]
    const size_t counts_b = (size_t)N * sizeof(int);          // 16B-multiple for N=100000
    const size_t xb_b     = (size_t)N * 128 * sizeof(unsigned short);
    const size_t need96   = counts_b + xb_b + (size_t)N * 96 * sizeof(int);
    const int cap = (ws_size >= need96) ? 96 : 64;            // deg~Poisson(32); 96 is ~certain

    int* counts = (int*)d_ws;
    unsigned short* Xb = (unsigned short*)((char*)d_ws + counts_b);
    int* bucket = (int*)((char*)d_ws + counts_b + xb_b);

    zero_counts<<<(N + 255) / 256, 256, 0, stream>>>(counts, N);

    const int total4 = (N * 128) / 4;
    x_to_bf16<<<(total4 + 255) / 256, 256, 0, stream>>>(X, Xb, total4);

    const int E4 = E / 4;            // E = 3.2M, divisible by 4
    fill_buckets<<<(E4 + 255) / 256, 256, 0, stream>>>(
        src, dst, counts, bucket, E4, N, cap);

    gather_gemm<<<(N + NODES_PER_BLOCK - 1) / NODES_PER_BLOCK, 128, 0, stream>>>(
        X, Xb, bucket, counts, W, bias, out, N, cap);
}

// Round 8
// 392.729 us; speedup vs baseline: 1.8050x; 1.5452x over previous
//
#include <hip/hip_runtime.h>
#include <cstddef>
#include <cstdint>

// Clique_GraphConv: out = relu(concat(X, scatter_mean(X[src], dst)) @ W + b)
// N = 100000, d = 128, E = 3.2M, W: [256,128] fp32.
//
// R8: kill fill_buckets' write amplification (R7: WRITE_SIZE 193MB ~= E*64B,
// scattered 4B stores). Two-pass partition sort:
//   part1: block-local LDS counting sort of 4096-edge chunks by dst>>8
//          (391 partitions), flushed as contiguous runs -> coalesced writes.
//   part2: one block/partition, LDS counting sort -> per-dst CSR lists in a
//          contiguous 32KB window (L2-resident, lines fully filled) + exact
//          deg/offsets.
// Gather (proven R7 config) walks CSR; Xb (bf16 X) aliases the dead
// partition buffer (x_to_bf16 runs after part2). Peak ws ~40.8MB (<51.6MB
// proven in R1/R5). Defensive clamps on all data-dependent indices.

#define NODES_PER_BLOCK 16
#define PART_SHIFT 8
#define PART_SZ 256          // nodes per partition
#define MAXP 448             // >= P = ceil(100000/256) = 391; scan covers 64*7
#define CHUNK 4096           // edges per part1 block
#define CAPP 8704            // records per partition region; mean 8192, +5.7 sigma

__device__ __forceinline__ int clampi(int v, int hi) {
    v = v < 0 ? 0 : v;
    return v >= hi ? hi - 1 : v;
}

__device__ __forceinline__ unsigned short bf16_rne(float f) {
    unsigned int u = __float_as_uint(f);
    unsigned int r = (u + 0x7FFFu + ((u >> 16) & 1u)) >> 16;
    return (unsigned short)r;
}

__device__ __forceinline__ void acc_bf16x8(float* a, uint4 r) {
    a[0] += __uint_as_float(r.x << 16);
    a[1] += __uint_as_float(r.x & 0xFFFF0000u);
    a[2] += __uint_as_float(r.y << 16);
    a[3] += __uint_as_float(r.y & 0xFFFF0000u);
    a[4] += __uint_as_float(r.z << 16);
    a[5] += __uint_as_float(r.z & 0xFFFF0000u);
    a[6] += __uint_as_float(r.w << 16);
    a[7] += __uint_as_float(r.w & 0xFFFF0000u);
}

__device__ __forceinline__ int wave_excl_scan64(int v, int lane) {
    int x = v;
#pragma unroll
    for (int off = 1; off < 64; off <<= 1) {
        int y = __shfl_up(x, off, 64);
        if (lane >= off) x += y;
    }
    return x - v;
}

__global__ void zero_cursors(int* __restrict__ c, int P) {
    int i = blockIdx.x * blockDim.x + threadIdx.x;
    if (i < P) c[i] = 0;
}

__global__ __launch_bounds__(256) void x_to_bf16(
    const float* __restrict__ X, unsigned short* __restrict__ Xb, int total4)
{
    int i = blockIdx.x * blockDim.x + threadIdx.x;
    if (i >= total4) return;
    float4 v = *(const float4*)(X + (size_t)i * 4);
    ushort4 o;
    o.x = bf16_rne(v.x); o.y = bf16_rne(v.y);
    o.z = bf16_rne(v.z); o.w = bf16_rne(v.w);
    *(ushort4*)(Xb + (size_t)i * 4) = o;
}

// ---- pass 1: partition edges by dst>>PART_SHIFT, coalesced flush ----
__global__ __launch_bounds__(256) void part1(
    const int* __restrict__ src, const int* __restrict__ dst,
    int* __restrict__ cursors, unsigned long long* __restrict__ parts,
    int E, int N, int P)
{
    __shared__ unsigned long long sbuf[CHUNK];      // 32 KB
    __shared__ int hist[MAXP], base_s[MAXP], hist2[MAXP], gbase[MAXP];
    const int tid = threadIdx.x;
    const int c0  = blockIdx.x * CHUNK;
    int cnt = E - c0; if (cnt > CHUNK) cnt = CHUNK;

    for (int i = tid; i < P; i += 256) { hist[i] = 0; hist2[i] = 0; }
    __syncthreads();

    int s[16], d[16];
#pragma unroll
    for (int k = 0; k < 16; ++k) {
        int i = k * 256 + tid;
        if (i < cnt) {
            int e = c0 + i;
            d[k] = clampi(dst[e], N);
            s[k] = clampi(src[e], N);
            atomicAdd(&hist[d[k] >> PART_SHIFT], 1);
        } else {
            d[k] = -1; s[k] = 0;
        }
    }
    __syncthreads();

    // exclusive scan hist -> base_s (wave 0: 64 lanes x 7 elems)
    if (tid < 64) {
        int pref[7]; int run = 0;
#pragma unroll
        for (int k2 = 0; k2 < 7; ++k2) {
            int idx = tid * 7 + k2;
            int v = (idx < P) ? hist[idx] : 0;
            pref[k2] = run; run += v;
        }
        int lx = wave_excl_scan64(run, tid);
#pragma unroll
        for (int k2 = 0; k2 < 7; ++k2) {
            int idx = tid * 7 + k2;
            if (idx < P) base_s[idx] = pref[k2] + lx;
        }
    }
    __syncthreads();

    // reserve per-partition global ranges
    for (int i = tid; i < P; i += 256) {
        int c = hist[i];
        gbase[i] = (c > 0) ? atomicAdd(&cursors[i], c) : 0;
    }
    __syncthreads();

    // scatter into LDS, sorted by partition
#pragma unroll
    for (int k = 0; k < 16; ++k) {
        if (d[k] >= 0) {
            int p = d[k] >> PART_SHIFT;
            int pos = atomicAdd(&hist2[p], 1) + base_s[p];
            sbuf[pos] = ((unsigned long long)(unsigned)d[k] << 32) |
                        (unsigned)s[k];
        }
    }
    __syncthreads();

    // coalesced flush: contiguous runs per partition
    for (int i = tid; i < cnt; i += 256) {
        unsigned long long rec = sbuf[i];
        int p = ((int)(rec >> 32)) >> PART_SHIFT;
        int gidx = gbase[p] + (i - base_s[p]);
        if (gidx < CAPP) parts[(size_t)p * CAPP + gidx] = rec;
    }
}

// ---- exclusive scan of per-partition counts -> CSR partition bases ----
__global__ void scan_pbase(const int* __restrict__ cursors,
                           int* __restrict__ pbase, int P)
{
    int tid = threadIdx.x;     // 64 threads
    int pref[7]; int run = 0;
#pragma unroll
    for (int k = 0; k < 7; ++k) {
        int idx = tid * 7 + k;
        int v = 0;
        if (idx < P) { v = cursors[idx]; if (v > CAPP) v = CAPP; }
        pref[k] = run; run += v;
    }
    int lx = wave_excl_scan64(run, tid);
#pragma unroll
    for (int k = 0; k < 7; ++k) {
        int idx = tid * 7 + k;
        if (idx < P) pbase[idx] = pref[k] + lx;
    }
}

// ---- pass 2: per-partition counting sort -> per-dst CSR + deg/offsets ----
__global__ __launch_bounds__(256) void part2(
    const unsigned long long* __restrict__ parts,
    const int* __restrict__ cursors, const int* __restrict__ pbase,
    int* __restrict__ csr, int* __restrict__ offsets, int* __restrict__ deg,
    int N, int P)
{
    __shared__ int ldeg[PART_SZ], loff[PART_SZ], lcur[PART_SZ];
    const int p   = blockIdx.x;
    const int tid = threadIdx.x;
    int cnt = cursors[p]; if (cnt > CAPP) cnt = CAPP;
    const int nbase = p << PART_SHIFT;
    const unsigned long long* prec = parts + (size_t)p * CAPP;

    ldeg[tid] = 0; lcur[tid] = 0;
    __syncthreads();
    for (int i = tid; i < cnt; i += 256) {
        int dl = ((int)(prec[i] >> 32)) & (PART_SZ - 1);
        atomicAdd(&ldeg[dl], 1);
    }
    __syncthreads();
    if (tid < 64) {   // exclusive scan ldeg -> loff (64 lanes x 4)
        int pref[4]; int run = 0;
#pragma unroll
        for (int k = 0; k < 4; ++k) { pref[k] = run; run += ldeg[tid * 4 + k]; }
        int lx = wave_excl_scan64(run, tid);
#pragma unroll
        for (int k = 0; k < 4; ++k) loff[tid * 4 + k] = pref[k] + lx;
    }
    __syncthreads();
    const int pb = pbase[p];
    const int n = nbase + tid;
    if (n < N) { offsets[n] = pb + loff[tid]; deg[n] = ldeg[tid]; }
    for (int i = tid; i < cnt; i += 256) {
        unsigned long long rec = prec[i];
        int dl = ((int)(rec >> 32)) & (PART_SZ - 1);
        int pos = atomicAdd(&lcur[dl], 1);
        csr[pb + loff[dl] + pos] = (int)(rec & 0xFFFFFFFFu);
    }
}

// ---- fused gather + GEMM (R7-proven config, CSR inputs) ----
__global__ __launch_bounds__(128) void gather_gemm(
    const float* __restrict__ X,
    const unsigned short* __restrict__ Xb,
    const int* __restrict__ csr,
    const int* __restrict__ offsets,
    const int* __restrict__ deg,
    const float* __restrict__ W,
    const float* __restrict__ bias,
    float* __restrict__ out, int N)
{
    __shared__ float H[NODES_PER_BLOCK][256];
    const int tid = threadIdx.x;
    const int n0  = blockIdx.x * NODES_PER_BLOCK;

    // ---- Phase A: 8 groups x 16 lanes; 16B bf16 loads, 4 rows in flight ----
    {
        const int sub = tid & 15;
        const int grp = tid >> 4;
        const int f0  = sub * 8;
        for (int ii = 0; ii < 2; ++ii) {
            const int i = grp * 2 + ii;
            const int n = n0 + i;
            if (n >= N) continue;
            const int dg = deg[n];
            int degc = dg < 0 ? 0 : dg;
            const int* brow = csr + offsets[n];
            float acc[8] = {0.f, 0.f, 0.f, 0.f, 0.f, 0.f, 0.f, 0.f};
            int t = 0;
            for (; t + 4 <= degc; t += 4) {
                int i0 = clampi(brow[t],     N);
                int i1 = clampi(brow[t + 1], N);
                int i2 = clampi(brow[t + 2], N);
                int i3 = clampi(brow[t + 3], N);
                uint4 r0 = *(const uint4*)(Xb + (size_t)i0 * 128 + f0);
                uint4 r1 = *(const uint4*)(Xb + (size_t)i1 * 128 + f0);
                uint4 r2 = *(const uint4*)(Xb + (size_t)i2 * 128 + f0);
                uint4 r3 = *(const uint4*)(Xb + (size_t)i3 * 128 + f0);
                acc_bf16x8(acc, r0);
                acc_bf16x8(acc, r1);
                acc_bf16x8(acc, r2);
                acc_bf16x8(acc, r3);
            }
            for (; t < degc; ++t) {
                int i0 = clampi(brow[t], N);
                uint4 r0 = *(const uint4*)(Xb + (size_t)i0 * 128 + f0);
                acc_bf16x8(acc, r0);
            }
            const float inv = 1.0f / fmaxf((float)dg, 1.0f);
            float4 s0 = *(const float4*)(X + (size_t)n * 128 + f0);
            float4 s1 = *(const float4*)(X + (size_t)n * 128 + f0 + 4);
            *(float4*)&H[i][f0]     = s0;
            *(float4*)&H[i][f0 + 4] = s1;
            float4 m0, m1;
            m0.x = acc[0] * inv; m0.y = acc[1] * inv;
            m0.z = acc[2] * inv; m0.w = acc[3] * inv;
            m1.x = acc[4] * inv; m1.y = acc[5] * inv;
            m1.z = acc[6] * inv; m1.w = acc[7] * inv;
            *(float4*)&H[i][128 + f0]     = m0;
            *(float4*)&H[i][128 + f0 + 4] = m1;
        }
    }
    __syncthreads();

    // ---- Phase B: out[n, j] = relu(sum_k H[n,k] * W[k,j] + b[j]) ----
    const int lane = tid & 31;
    const int grp  = tid >> 5;
    const int j0 = lane * 4;
    float4 bb = *(const float4*)(bias + j0);
    float4 a0 = bb, a1 = bb, a2 = bb, a3 = bb;
    const float* h0p = &H[grp * 4 + 0][0];
    const float* h1p = &H[grp * 4 + 1][0];
    const float* h2p = &H[grp * 4 + 2][0];
    const float* h3p = &H[grp * 4 + 3][0];
#pragma unroll 4
    for (int k = 0; k < 256; ++k) {
        float4 w = *(const float4*)(W + (size_t)k * 128 + j0);
        float h0 = h0p[k], h1 = h1p[k], h2 = h2p[k], h3 = h3p[k];
        a0.x += h0 * w.x; a0.y += h0 * w.y; a0.z += h0 * w.z; a0.w += h0 * w.w;
        a1.x += h1 * w.x; a1.y += h1 * w.y; a1.z += h1 * w.z; a1.w += h1 * w.w;
        a2.x += h2 * w.x; a2.y += h2 * w.y; a2.z += h2 * w.z; a2.w += h2 * w.w;
        a3.x += h3 * w.x; a3.y += h3 * w.y; a3.z += h3 * w.z; a3.w += h3 * w.w;
    }
    float4 accs[4] = {a0, a1, a2, a3};
#pragma unroll
    for (int i = 0; i < 4; ++i) {
        int n = n0 + grp * 4 + i;
        if (n < N) {
            float4 r = accs[i];
            r.x = fmaxf(r.x, 0.f);
            r.y = fmaxf(r.y, 0.f);
            r.z = fmaxf(r.z, 0.f);
            r.w = fmaxf(r.w, 0.f);
            *(float4*)(out + (size_t)n * 128 + j0) = r;
        }
    }
}

static inline size_t align256(size_t x) { return (x + 255) & ~(size_t)255; }

extern "C" void kernel_launch(void* const* d_in, const int* in_sizes, int n_in,
                              void* d_out, int out_size, void* d_ws, size_t ws_size,
                              hipStream_t stream) {
    const float* X    = (const float*)d_in[0];
    const int*   src  = (const int*)d_in[1];
    const int*   dst  = (const int*)d_in[2];
    const float* W    = (const float*)d_in[3];
    const float* bias = (const float*)d_in[4];
    float* out = (float*)d_out;

    const int N = in_sizes[0] / 128;
    const int E = in_sizes[1];
    const int P = (N + PART_SZ - 1) >> PART_SHIFT;   // 391

    // Workspace (all 256B-aligned):
    // cursors[P] | pbase[P] | deg[N] | offsets[N] | csr[E] | partsArea
    // partsArea holds parts (live part1..part2) then Xb (live after part2).
    char* base = (char*)d_ws;
    size_t o_cursors = 0;
    size_t o_pbase   = o_cursors + align256((size_t)P * 4);
    size_t o_deg     = o_pbase   + align256((size_t)P * 4);
    size_t o_off     = o_deg     + align256((size_t)N * 4);
    size_t o_csr     = o_off     + align256((size_t)N * 4);
    size_t o_parts   = o_csr     + align256((size_t)E * 4);

    int* cursors = (int*)(base + o_cursors);
    int* pbase   = (int*)(base + o_pbase);
    int* deg     = (int*)(base + o_deg);
    int* offsets = (int*)(base + o_off);
    int* csr     = (int*)(base + o_csr);
    unsigned long long* parts = (unsigned long long*)(base + o_parts);
    unsigned short* Xb = (unsigned short*)(base + o_parts);   // aliases parts

    zero_cursors<<<(P + 255) / 256, 256, 0, stream>>>(cursors, P);

    part1<<<(E + CHUNK - 1) / CHUNK, 256, 0, stream>>>(
        src, dst, cursors, parts, E, N, P);

    scan_pbase<<<1, 64, 0, stream>>>(cursors, pbase, P);

    part2<<<P, 256, 0, stream>>>(parts, cursors, pbase, csr, offsets, deg, N, P);

    const int total4 = (N * 128) / 4;
    x_to_bf16<<<(total4 + 255) / 256, 256, 0, stream>>>(X, Xb, total4);

    gather_gemm<<<(N + NODES_PER_BLOCK - 1) / NODES_PER_BLOCK, 128, 0, stream>>>(
        X, Xb, csr, offsets, deg, W, bias, out, N);
}

// Round 9
// 316.244 us; speedup vs baseline: 2.2415x; 1.2419x over previous
//
#include <hip/hip_runtime.h>
#include <cstddef>
#include <cstdint>

// Clique_GraphConv: out = relu(concat(X, scatter_mean(X[src], dst)) @ W + b)
// N = 100000, d = 128, E = 3.2M, W: [256,128] fp32.
//
// R9 = R8 partition-sort pipeline + three gather_gemm upgrades:
//  (1) Phase B GEMM via mfma_f32_16x16x32_bf16 (H staged bf16 in LDS, W
//      pre-swizzled to B-fragment order -> one 16B coalesced load per frag).
//      42us fp32-VALU floor -> ~5us MFMA.
//  (2) Phase A: 8 rows in flight (was 4); clamps dropped on CSR entries
//      (CSR built from clamped values, provably in-range).
//  (3) Self features read from Xb (bf16) -- removes the fp32 X stream.
// Layouts (guide §3, m89/m120-verified): A[m=lane&15][k=quad*8+j],
// B[k=quad*8+j][n=lane&15], D col=lane&15 row=quad*4+reg.

#define NODES_PER_BLOCK 16
#define PART_SHIFT 8
#define PART_SZ 256          // nodes per partition
#define MAXP 448             // >= P = ceil(100000/256) = 391
#define CHUNK 4096           // edges per part1 block
#define CAPP 8704            // records/partition; mean 8192, +5.7 sigma

typedef __attribute__((ext_vector_type(8))) short bf16x8;
typedef __attribute__((ext_vector_type(4))) float f32x4;

__device__ __forceinline__ int clampi(int v, int hi) {
    v = v < 0 ? 0 : v;
    return v >= hi ? hi - 1 : v;
}

__device__ __forceinline__ unsigned short bf16_rne(float f) {
    unsigned int u = __float_as_uint(f);
    unsigned int r = (u + 0x7FFFu + ((u >> 16) & 1u)) >> 16;
    return (unsigned short)r;
}

__device__ __forceinline__ unsigned pack2(float a, float b) {
    return (unsigned)bf16_rne(a) | ((unsigned)bf16_rne(b) << 16);
}

__device__ __forceinline__ void acc_bf16x8(float* a, uint4 r) {
    a[0] += __uint_as_float(r.x << 16);
    a[1] += __uint_as_float(r.x & 0xFFFF0000u);
    a[2] += __uint_as_float(r.y << 16);
    a[3] += __uint_as_float(r.y & 0xFFFF0000u);
    a[4] += __uint_as_float(r.z << 16);
    a[5] += __uint_as_float(r.z & 0xFFFF0000u);
    a[6] += __uint_as_float(r.w << 16);
    a[7] += __uint_as_float(r.w & 0xFFFF0000u);
}

__device__ __forceinline__ int wave_excl_scan64(int v, int lane) {
    int x = v;
#pragma unroll
    for (int off = 1; off < 64; off <<= 1) {
        int y = __shfl_up(x, off, 64);
        if (lane >= off) x += y;
    }
    return x - v;
}

__global__ void zero_cursors(int* __restrict__ c, int P) {
    int i = blockIdx.x * blockDim.x + threadIdx.x;
    if (i < P) c[i] = 0;
}

// X -> bf16 copy; W -> bf16 + swizzle to B-fragment order:
// Wswz[((kk*8+cg)*64 + (q*16+nn))*8 + j] = W[kk*32+q*8+j][cg*16+nn]
__global__ __launch_bounds__(256) void xw_to_bf16(
    const float* __restrict__ X, unsigned short* __restrict__ Xb, int total4,
    const float* __restrict__ W, unsigned short* __restrict__ Wswz)
{
    int i = blockIdx.x * blockDim.x + threadIdx.x;
    if (i < 256 * 128) {
        int k = i >> 7, n = i & 127;
        int kk = k >> 5, q = (k >> 3) & 3, j = k & 7;
        int cg = n >> 4, nn = n & 15;
        int lane = q * 16 + nn;
        Wswz[((size_t)(kk * 8 + cg) * 64 + lane) * 8 + j] =
            bf16_rne(W[(size_t)k * 128 + n]);
    }
    if (i < total4) {
        float4 v = *(const float4*)(X + (size_t)i * 4);
        ushort4 o;
        o.x = bf16_rne(v.x); o.y = bf16_rne(v.y);
        o.z = bf16_rne(v.z); o.w = bf16_rne(v.w);
        *(ushort4*)(Xb + (size_t)i * 4) = o;
    }
}

// ---- pass 1: partition edges by dst>>PART_SHIFT, coalesced flush ----
__global__ __launch_bounds__(256) void part1(
    const int* __restrict__ src, const int* __restrict__ dst,
    int* __restrict__ cursors, unsigned long long* __restrict__ parts,
    int E, int N, int P)
{
    __shared__ unsigned long long sbuf[CHUNK];      // 32 KB
    __shared__ int hist[MAXP], base_s[MAXP], hist2[MAXP], gbase[MAXP];
    const int tid = threadIdx.x;
    const int c0  = blockIdx.x * CHUNK;
    int cnt = E - c0; if (cnt > CHUNK) cnt = CHUNK;

    for (int i = tid; i < P; i += 256) { hist[i] = 0; hist2[i] = 0; }
    __syncthreads();

    int s[16], d[16];
#pragma unroll
    for (int k = 0; k < 16; ++k) {
        int i = k * 256 + tid;
        if (i < cnt) {
            int e = c0 + i;
            d[k] = clampi(dst[e], N);
            s[k] = clampi(src[e], N);
            atomicAdd(&hist[d[k] >> PART_SHIFT], 1);
        } else {
            d[k] = -1; s[k] = 0;
        }
    }
    __syncthreads();

    if (tid < 64) {        // exclusive scan hist -> base_s
        int pref[7]; int run = 0;
#pragma unroll
        for (int k2 = 0; k2 < 7; ++k2) {
            int idx = tid * 7 + k2;
            int v = (idx < P) ? hist[idx] : 0;
            pref[k2] = run; run += v;
        }
        int lx = wave_excl_scan64(run, tid);
#pragma unroll
        for (int k2 = 0; k2 < 7; ++k2) {
            int idx = tid * 7 + k2;
            if (idx < P) base_s[idx] = pref[k2] + lx;
        }
    }
    __syncthreads();

    for (int i = tid; i < P; i += 256) {
        int c = hist[i];
        gbase[i] = (c > 0) ? atomicAdd(&cursors[i], c) : 0;
    }
    __syncthreads();

#pragma unroll
    for (int k = 0; k < 16; ++k) {
        if (d[k] >= 0) {
            int p = d[k] >> PART_SHIFT;
            int pos = atomicAdd(&hist2[p], 1) + base_s[p];
            sbuf[pos] = ((unsigned long long)(unsigned)d[k] << 32) |
                        (unsigned)s[k];
        }
    }
    __syncthreads();

    for (int i = tid; i < cnt; i += 256) {
        unsigned long long rec = sbuf[i];
        int p = ((int)(rec >> 32)) >> PART_SHIFT;
        int gidx = gbase[p] + (i - base_s[p]);
        if (gidx < CAPP) parts[(size_t)p * CAPP + gidx] = rec;
    }
}

__global__ void scan_pbase(const int* __restrict__ cursors,
                           int* __restrict__ pbase, int P)
{
    int tid = threadIdx.x;     // 64 threads
    int pref[7]; int run = 0;
#pragma unroll
    for (int k = 0; k < 7; ++k) {
        int idx = tid * 7 + k;
        int v = 0;
        if (idx < P) { v = cursors[idx]; if (v > CAPP) v = CAPP; }
        pref[k] = run; run += v;
    }
    int lx = wave_excl_scan64(run, tid);
#pragma unroll
    for (int k = 0; k < 7; ++k) {
        int idx = tid * 7 + k;
        if (idx < P) pbase[idx] = pref[k] + lx;
    }
}

// ---- pass 2: per-partition counting sort -> per-dst CSR + deg/offsets ----
__global__ __launch_bounds__(256) void part2(
    const unsigned long long* __restrict__ parts,
    const int* __restrict__ cursors, const int* __restrict__ pbase,
    int* __restrict__ csr, int* __restrict__ offsets, int* __restrict__ deg,
    int N, int P)
{
    __shared__ int ldeg[PART_SZ], loff[PART_SZ], lcur[PART_SZ];
    const int p   = blockIdx.x;
    const int tid = threadIdx.x;
    int cnt = cursors[p]; if (cnt > CAPP) cnt = CAPP;
    const int nbase = p << PART_SHIFT;
    const unsigned long long* prec = parts + (size_t)p * CAPP;

    ldeg[tid] = 0; lcur[tid] = 0;
    __syncthreads();
    for (int i = tid; i < cnt; i += 256) {
        int dl = ((int)(prec[i] >> 32)) & (PART_SZ - 1);
        atomicAdd(&ldeg[dl], 1);
    }
    __syncthreads();
    if (tid < 64) {
        int pref[4]; int run = 0;
#pragma unroll
        for (int k = 0; k < 4; ++k) { pref[k] = run; run += ldeg[tid * 4 + k]; }
        int lx = wave_excl_scan64(run, tid);
#pragma unroll
        for (int k = 0; k < 4; ++k) loff[tid * 4 + k] = pref[k] + lx;
    }
    __syncthreads();
    const int pb = pbase[p];
    const int n = nbase + tid;
    if (n < N) { offsets[n] = pb + loff[tid]; deg[n] = ldeg[tid]; }
    for (int i = tid; i < cnt; i += 256) {
        unsigned long long rec = prec[i];
        int dl = ((int)(rec >> 32)) & (PART_SZ - 1);
        int pos = atomicAdd(&lcur[dl], 1);
        csr[pb + loff[dl] + pos] = (int)(rec & 0xFFFFFFFFu);
    }
}

// ---- fused gather (bf16, 8 rows in flight) + MFMA GEMM ----
__global__ __launch_bounds__(128) void gather_gemm(
    const unsigned short* __restrict__ Xb,
    const int* __restrict__ csr,
    const int* __restrict__ offsets,
    const int* __restrict__ deg,
    const unsigned short* __restrict__ Wswz,
    const float* __restrict__ bias,
    float* __restrict__ out, int N)
{
    __shared__ unsigned short Hb[NODES_PER_BLOCK][256];   // 8 KB
    const int tid = threadIdx.x;
    const int n0  = blockIdx.x * NODES_PER_BLOCK;

    // ---- Phase A: 8 groups x 16 lanes; 2 nodes/group; 8 rows in flight ----
    {
        const int sub = tid & 15;
        const int grp = tid >> 4;
        const int f0  = sub * 8;
        for (int ii = 0; ii < 2; ++ii) {
            const int i = grp * 2 + ii;
            const int n = n0 + i;
            if (n >= N) continue;
            const int dg = deg[n];
            const int* brow = csr + offsets[n];
            float acc[8] = {0.f, 0.f, 0.f, 0.f, 0.f, 0.f, 0.f, 0.f};
            int t = 0;
            for (; t + 8 <= dg; t += 8) {
                int i0 = brow[t],     i1 = brow[t + 1];
                int i2 = brow[t + 2], i3 = brow[t + 3];
                int i4 = brow[t + 4], i5 = brow[t + 5];
                int i6 = brow[t + 6], i7 = brow[t + 7];
                uint4 r0 = *(const uint4*)(Xb + (size_t)i0 * 128 + f0);
                uint4 r1 = *(const uint4*)(Xb + (size_t)i1 * 128 + f0);
                uint4 r2 = *(const uint4*)(Xb + (size_t)i2 * 128 + f0);
                uint4 r3 = *(const uint4*)(Xb + (size_t)i3 * 128 + f0);
                uint4 r4 = *(const uint4*)(Xb + (size_t)i4 * 128 + f0);
                uint4 r5 = *(const uint4*)(Xb + (size_t)i5 * 128 + f0);
                uint4 r6 = *(const uint4*)(Xb + (size_t)i6 * 128 + f0);
                uint4 r7 = *(const uint4*)(Xb + (size_t)i7 * 128 + f0);
                acc_bf16x8(acc, r0); acc_bf16x8(acc, r1);
                acc_bf16x8(acc, r2); acc_bf16x8(acc, r3);
                acc_bf16x8(acc, r4); acc_bf16x8(acc, r5);
                acc_bf16x8(acc, r6); acc_bf16x8(acc, r7);
            }
            for (; t + 4 <= dg; t += 4) {
                int i0 = brow[t],     i1 = brow[t + 1];
                int i2 = brow[t + 2], i3 = brow[t + 3];
                uint4 r0 = *(const uint4*)(Xb + (size_t)i0 * 128 + f0);
                uint4 r1 = *(const uint4*)(Xb + (size_t)i1 * 128 + f0);
                uint4 r2 = *(const uint4*)(Xb + (size_t)i2 * 128 + f0);
                uint4 r3 = *(const uint4*)(Xb + (size_t)i3 * 128 + f0);
                acc_bf16x8(acc, r0); acc_bf16x8(acc, r1);
                acc_bf16x8(acc, r2); acc_bf16x8(acc, r3);
            }
            for (; t < dg; ++t) {
                uint4 r0 = *(const uint4*)(Xb + (size_t)brow[t] * 128 + f0);
                acc_bf16x8(acc, r0);
            }
            const float inv = 1.0f / fmaxf((float)dg, 1.0f);
            // self features (bf16 passthrough)
            *(uint4*)&Hb[i][f0] = *(const uint4*)(Xb + (size_t)n * 128 + f0);
            // neighbor mean -> bf16
            uint4 mo;
            mo.x = pack2(acc[0] * inv, acc[1] * inv);
            mo.y = pack2(acc[2] * inv, acc[3] * inv);
            mo.z = pack2(acc[4] * inv, acc[5] * inv);
            mo.w = pack2(acc[6] * inv, acc[7] * inv);
            *(uint4*)&Hb[i][128 + f0] = mo;
        }
    }
    __syncthreads();

    // ---- Phase B: MFMA 16x16x32 bf16. Wave wv covers cols wv*64..wv*64+63.
    const int lane = tid & 63;
    const int wv   = tid >> 6;
    const int m    = lane & 15;
    const int quad = lane >> 4;
    f32x4 acc0 = {0.f, 0.f, 0.f, 0.f};
    f32x4 acc1 = {0.f, 0.f, 0.f, 0.f};
    f32x4 acc2 = {0.f, 0.f, 0.f, 0.f};
    f32x4 acc3 = {0.f, 0.f, 0.f, 0.f};
#pragma unroll
    for (int kk = 0; kk < 8; ++kk) {
        bf16x8 a = *(const bf16x8*)&Hb[m][kk * 32 + quad * 8];
        const unsigned short* wp =
            Wswz + ((size_t)(kk * 8 + wv * 4) * 64 + lane) * 8;
        bf16x8 b0 = *(const bf16x8*)(wp);
        bf16x8 b1 = *(const bf16x8*)(wp + 64 * 8);
        bf16x8 b2 = *(const bf16x8*)(wp + 2 * 64 * 8);
        bf16x8 b3 = *(const bf16x8*)(wp + 3 * 64 * 8);
        acc0 = __builtin_amdgcn_mfma_f32_16x16x32_bf16(a, b0, acc0, 0, 0, 0);
        acc1 = __builtin_amdgcn_mfma_f32_16x16x32_bf16(a, b1, acc1, 0, 0, 0);
        acc2 = __builtin_amdgcn_mfma_f32_16x16x32_bf16(a, b2, acc2, 0, 0, 0);
        acc3 = __builtin_amdgcn_mfma_f32_16x16x32_bf16(a, b3, acc3, 0, 0, 0);
    }
    f32x4 accs[4] = {acc0, acc1, acc2, acc3};
#pragma unroll
    for (int c = 0; c < 4; ++c) {
        int feat = wv * 64 + c * 16 + m;
        float bv = bias[feat];
#pragma unroll
        for (int r = 0; r < 4; ++r) {
            int node = n0 + quad * 4 + r;
            if (node < N)
                out[(size_t)node * 128 + feat] = fmaxf(accs[c][r] + bv, 0.f);
        }
    }
}

static inline size_t align256(size_t x) { return (x + 255) & ~(size_t)255; }

extern "C" void kernel_launch(void* const* d_in, const int* in_sizes, int n_in,
                              void* d_out, int out_size, void* d_ws, size_t ws_size,
                              hipStream_t stream) {
    const float* X    = (const float*)d_in[0];
    const int*   src  = (const int*)d_in[1];
    const int*   dst  = (const int*)d_in[2];
    const float* W    = (const float*)d_in[3];
    const float* bias = (const float*)d_in[4];
    float* out = (float*)d_out;

    const int N = in_sizes[0] / 128;
    const int E = in_sizes[1];
    const int P = (N + PART_SZ - 1) >> PART_SHIFT;   // 391

    // Workspace (256B-aligned):
    // cursors[P] | pbase[P] | deg[N] | offsets[N] | csr[E] | partsArea
    // partsArea (27.2MB): parts live part1..part2; then Xb (25.6MB) + Wswz
    // (64KB) alias it after part2.
    char* base = (char*)d_ws;
    size_t o_cursors = 0;
    size_t o_pbase   = o_cursors + align256((size_t)P * 4);
    size_t o_deg     = o_pbase   + align256((size_t)P * 4);
    size_t o_off     = o_deg     + align256((size_t)N * 4);
    size_t o_csr     = o_off     + align256((size_t)N * 4);
    size_t o_parts   = o_csr     + align256((size_t)E * 4);
    size_t o_wswz    = o_parts   + align256((size_t)N * 128 * 2);

    int* cursors = (int*)(base + o_cursors);
    int* pbase   = (int*)(base + o_pbase);
    int* deg     = (int*)(base + o_deg);
    int* offsets = (int*)(base + o_off);
    int* csr     = (int*)(base + o_csr);
    unsigned long long* parts = (unsigned long long*)(base + o_parts);
    unsigned short* Xb   = (unsigned short*)(base + o_parts);   // aliases parts
    unsigned short* Wswz = (unsigned short*)(base + o_wswz);    // after Xb

    zero_cursors<<<(P + 255) / 256, 256, 0, stream>>>(cursors, P);

    part1<<<(E + CHUNK - 1) / CHUNK, 256, 0, stream>>>(
        src, dst, cursors, parts, E, N, P);

    scan_pbase<<<1, 64, 0, stream>>>(cursors, pbase, P);

    part2<<<P, 256, 0, stream>>>(parts, cursors, pbase, csr, offsets, deg, N, P);

    const int total4 = (N * 128) / 4;
    xw_to_bf16<<<(total4 + 255) / 256, 256, 0, stream>>>(X, Xb, total4, W, Wswz);

    gather_gemm<<<(N + NODES_PER_BLOCK - 1) / NODES_PER_BLOCK, 128, 0, stream>>>(
        Xb, csr, offsets, deg, Wswz, bias, out, N);
}

// Round 10
// 312.701 us; speedup vs baseline: 2.2669x; 1.0113x over previous
//
#include <hip/hip_runtime.h>
#include <cstddef>
#include <cstdint>

// Clique_GraphConv: out = relu(concat(X, scatter_mean(X[src], dst)) @ W + b)
// N = 100000, d = 128, E = 3.2M, W: [256,128] fp32.
//
// R10 = R9 with a preprocessing overhaul (numerics identical):
//  (1) part1 uses ONE LDS-atomic pass (atomicAdd's return value is the
//      stable rank) -- was two passes / 6.4M LDS atomics.
//  (2) CSR is partition-strided (offsets[n] = p*CAPP + loff) -> scan_pbase
//      kernel deleted.
//  (3) xw_to_bf16 fused into the part1 launch as extra blocks (needs
//      un-aliased Xb; guarded by ws_size, fallback = R9's aliased ordering).
// gather_gemm unchanged from R9 (136us, MFMA epilogue).

#define NODES_PER_BLOCK 16
#define PART_SHIFT 8
#define PART_SZ 256          // nodes per partition
#define MAXP 448             // >= P = ceil(100000/256) = 391
#define CHUNK 4096           // edges per part1 block
#define CAPP 8704            // records/partition; mean 8192, +5.7 sigma

typedef __attribute__((ext_vector_type(8))) short bf16x8;
typedef __attribute__((ext_vector_type(4))) float f32x4;

__device__ __forceinline__ int clampi(int v, int hi) {
    v = v < 0 ? 0 : v;
    return v >= hi ? hi - 1 : v;
}

__device__ __forceinline__ unsigned short bf16_rne(float f) {
    unsigned int u = __float_as_uint(f);
    unsigned int r = (u + 0x7FFFu + ((u >> 16) & 1u)) >> 16;
    return (unsigned short)r;
}

__device__ __forceinline__ unsigned pack2(float a, float b) {
    return (unsigned)bf16_rne(a) | ((unsigned)bf16_rne(b) << 16);
}

__device__ __forceinline__ void acc_bf16x8(float* a, uint4 r) {
    a[0] += __uint_as_float(r.x << 16);
    a[1] += __uint_as_float(r.x & 0xFFFF0000u);
    a[2] += __uint_as_float(r.y << 16);
    a[3] += __uint_as_float(r.y & 0xFFFF0000u);
    a[4] += __uint_as_float(r.z << 16);
    a[5] += __uint_as_float(r.z & 0xFFFF0000u);
    a[6] += __uint_as_float(r.w << 16);
    a[7] += __uint_as_float(r.w & 0xFFFF0000u);
}

__device__ __forceinline__ int wave_excl_scan64(int v, int lane) {
    int x = v;
#pragma unroll
    for (int off = 1; off < 64; off <<= 1) {
        int y = __shfl_up(x, off, 64);
        if (lane >= off) x += y;
    }
    return x - v;
}

__global__ void zero_cursors(int* __restrict__ c, int P) {
    int i = blockIdx.x * blockDim.x + threadIdx.x;
    if (i < P) c[i] = 0;
}

// ---- device helpers for the fused pre1 kernel ----
__device__ void do_xw_block(int xb,                 // xw-block index
    const float* __restrict__ X, unsigned short* __restrict__ Xb, int total4,
    const float* __restrict__ W, unsigned short* __restrict__ Wswz)
{
    int i = xb * 256 + threadIdx.x;
    if (i < 256 * 128) {     // W -> bf16 swizzled to B-fragment order
        int k = i >> 7, n = i & 127;
        int kk = k >> 5, q = (k >> 3) & 3, j = k & 7;
        int cg = n >> 4, nn = n & 15;
        int lane = q * 16 + nn;
        Wswz[((size_t)(kk * 8 + cg) * 64 + lane) * 8 + j] =
            bf16_rne(W[(size_t)k * 128 + n]);
    }
    if (i < total4) {
        float4 v = *(const float4*)(X + (size_t)i * 4);
        ushort4 o;
        o.x = bf16_rne(v.x); o.y = bf16_rne(v.y);
        o.z = bf16_rne(v.z); o.w = bf16_rne(v.w);
        *(ushort4*)(Xb + (size_t)i * 4) = o;
    }
}

// pre1: blocks [0, nPart1) do the partition pass; blocks [nPart1, ...) do
// the X/W bf16 conversion. Independent work, one launch.
__global__ __launch_bounds__(256) void pre1(
    const int* __restrict__ src, const int* __restrict__ dst,
    int* __restrict__ cursors, unsigned long long* __restrict__ parts,
    int E, int N, int P, int nPart1,
    const float* __restrict__ X, unsigned short* __restrict__ Xb, int total4,
    const float* __restrict__ W, unsigned short* __restrict__ Wswz)
{
    if ((int)blockIdx.x >= nPart1) {
        do_xw_block((int)blockIdx.x - nPart1, X, Xb, total4, W, Wswz);
        return;
    }
    __shared__ unsigned long long sbuf[CHUNK];      // 32 KB
    __shared__ int hist[MAXP], base_s[MAXP], gbase[MAXP];
    const int tid = threadIdx.x;
    const int c0  = blockIdx.x * CHUNK;
    int cnt = E - c0; if (cnt > CHUNK) cnt = CHUNK;

    for (int i = tid; i < P; i += 256) hist[i] = 0;
    __syncthreads();

    int s[16], d[16], r[16];
#pragma unroll
    for (int k = 0; k < 16; ++k) {
        int i = k * 256 + tid;
        if (i < cnt) {
            int e = c0 + i;
            d[k] = clampi(dst[e], N);
            s[k] = clampi(src[e], N);
            r[k] = atomicAdd(&hist[d[k] >> PART_SHIFT], 1);   // rank!
        } else {
            d[k] = -1; s[k] = 0; r[k] = 0;
        }
    }
    __syncthreads();

    if (tid < 64) {        // exclusive scan hist -> base_s
        int pref[7]; int run = 0;
#pragma unroll
        for (int k2 = 0; k2 < 7; ++k2) {
            int idx = tid * 7 + k2;
            int v = (idx < P) ? hist[idx] : 0;
            pref[k2] = run; run += v;
        }
        int lx = wave_excl_scan64(run, tid);
#pragma unroll
        for (int k2 = 0; k2 < 7; ++k2) {
            int idx = tid * 7 + k2;
            if (idx < P) base_s[idx] = pref[k2] + lx;
        }
    }
    __syncthreads();

    for (int i = tid; i < P; i += 256) {
        int c = hist[i];
        gbase[i] = (c > 0) ? atomicAdd(&cursors[i], c) : 0;
    }
    __syncthreads();

#pragma unroll
    for (int k = 0; k < 16; ++k) {
        if (d[k] >= 0) {
            int p = d[k] >> PART_SHIFT;
            sbuf[base_s[p] + r[k]] =
                ((unsigned long long)(unsigned)d[k] << 32) | (unsigned)s[k];
        }
    }
    __syncthreads();

    for (int i = tid; i < cnt; i += 256) {
        unsigned long long rec = sbuf[i];
        int p = ((int)(rec >> 32)) >> PART_SHIFT;
        int gidx = gbase[p] + (i - base_s[p]);
        if (gidx < CAPP) parts[(size_t)p * CAPP + gidx] = rec;
    }
}

// ---- pass 2: per-partition counting sort -> per-dst CSR (strided layout) ----
__global__ __launch_bounds__(256) void part2(
    const unsigned long long* __restrict__ parts,
    const int* __restrict__ cursors,
    int* __restrict__ csr, int* __restrict__ offsets, int* __restrict__ deg,
    int N, int P)
{
    __shared__ int ldeg[PART_SZ], loff[PART_SZ], lcur[PART_SZ];
    const int p   = blockIdx.x;
    const int tid = threadIdx.x;
    int cnt = cursors[p]; if (cnt > CAPP) cnt = CAPP;
    const int nbase = p << PART_SHIFT;
    const unsigned long long* prec = parts + (size_t)p * CAPP;

    ldeg[tid] = 0; lcur[tid] = 0;
    __syncthreads();
    for (int i = tid; i < cnt; i += 256) {
        int dl = ((int)(prec[i] >> 32)) & (PART_SZ - 1);
        atomicAdd(&ldeg[dl], 1);
    }
    __syncthreads();
    if (tid < 64) {
        int pref[4]; int run = 0;
#pragma unroll
        for (int k = 0; k < 4; ++k) { pref[k] = run; run += ldeg[tid * 4 + k]; }
        int lx = wave_excl_scan64(run, tid);
#pragma unroll
        for (int k = 0; k < 4; ++k) loff[tid * 4 + k] = pref[k] + lx;
    }
    __syncthreads();
    const int pb = p * CAPP;          // strided CSR: no global scan needed
    const int n = nbase + tid;
    if (n < N) { offsets[n] = pb + loff[tid]; deg[n] = ldeg[tid]; }
    for (int i = tid; i < cnt; i += 256) {
        unsigned long long rec = prec[i];
        int dl = ((int)(rec >> 32)) & (PART_SZ - 1);
        int pos = atomicAdd(&lcur[dl], 1);
        csr[pb + loff[dl] + pos] = (int)(rec & 0xFFFFFFFFu);
    }
}

// ---- fused gather (bf16, 8 rows in flight) + MFMA GEMM (R9-proven) ----
__global__ __launch_bounds__(128) void gather_gemm(
    const unsigned short* __restrict__ Xb,
    const int* __restrict__ csr,
    const int* __restrict__ offsets,
    const int* __restrict__ deg,
    const unsigned short* __restrict__ Wswz,
    const float* __restrict__ bias,
    float* __restrict__ out, int N)
{
    __shared__ unsigned short Hb[NODES_PER_BLOCK][256];   // 8 KB
    const int tid = threadIdx.x;
    const int n0  = blockIdx.x * NODES_PER_BLOCK;

    {
        const int sub = tid & 15;
        const int grp = tid >> 4;
        const int f0  = sub * 8;
        for (int ii = 0; ii < 2; ++ii) {
            const int i = grp * 2 + ii;
            const int n = n0 + i;
            if (n >= N) continue;
            const int dg = deg[n];
            const int* brow = csr + offsets[n];
            float acc[8] = {0.f, 0.f, 0.f, 0.f, 0.f, 0.f, 0.f, 0.f};
            int t = 0;
            for (; t + 8 <= dg; t += 8) {
                int i0 = brow[t],     i1 = brow[t + 1];
                int i2 = brow[t + 2], i3 = brow[t + 3];
                int i4 = brow[t + 4], i5 = brow[t + 5];
                int i6 = brow[t + 6], i7 = brow[t + 7];
                uint4 r0 = *(const uint4*)(Xb + (size_t)i0 * 128 + f0);
                uint4 r1 = *(const uint4*)(Xb + (size_t)i1 * 128 + f0);
                uint4 r2 = *(const uint4*)(Xb + (size_t)i2 * 128 + f0);
                uint4 r3 = *(const uint4*)(Xb + (size_t)i3 * 128 + f0);
                uint4 r4 = *(const uint4*)(Xb + (size_t)i4 * 128 + f0);
                uint4 r5 = *(const uint4*)(Xb + (size_t)i5 * 128 + f0);
                uint4 r6 = *(const uint4*)(Xb + (size_t)i6 * 128 + f0);
                uint4 r7 = *(const uint4*)(Xb + (size_t)i7 * 128 + f0);
                acc_bf16x8(acc, r0); acc_bf16x8(acc, r1);
                acc_bf16x8(acc, r2); acc_bf16x8(acc, r3);
                acc_bf16x8(acc, r4); acc_bf16x8(acc, r5);
                acc_bf16x8(acc, r6); acc_bf16x8(acc, r7);
            }
            for (; t + 4 <= dg; t += 4) {
                int i0 = brow[t],     i1 = brow[t + 1];
                int i2 = brow[t + 2], i3 = brow[t + 3];
                uint4 r0 = *(const uint4*)(Xb + (size_t)i0 * 128 + f0);
                uint4 r1 = *(const uint4*)(Xb + (size_t)i1 * 128 + f0);
                uint4 r2 = *(const uint4*)(Xb + (size_t)i2 * 128 + f0);
                uint4 r3 = *(const uint4*)(Xb + (size_t)i3 * 128 + f0);
                acc_bf16x8(acc, r0); acc_bf16x8(acc, r1);
                acc_bf16x8(acc, r2); acc_bf16x8(acc, r3);
            }
            for (; t < dg; ++t) {
                uint4 r0 = *(const uint4*)(Xb + (size_t)brow[t] * 128 + f0);
                acc_bf16x8(acc, r0);
            }
            const float inv = 1.0f / fmaxf((float)dg, 1.0f);
            *(uint4*)&Hb[i][f0] = *(const uint4*)(Xb + (size_t)n * 128 + f0);
            uint4 mo;
            mo.x = pack2(acc[0] * inv, acc[1] * inv);
            mo.y = pack2(acc[2] * inv, acc[3] * inv);
            mo.z = pack2(acc[4] * inv, acc[5] * inv);
            mo.w = pack2(acc[6] * inv, acc[7] * inv);
            *(uint4*)&Hb[i][128 + f0] = mo;
        }
    }
    __syncthreads();

    const int lane = tid & 63;
    const int wv   = tid >> 6;
    const int m    = lane & 15;
    const int quad = lane >> 4;
    f32x4 acc0 = {0.f, 0.f, 0.f, 0.f};
    f32x4 acc1 = {0.f, 0.f, 0.f, 0.f};
    f32x4 acc2 = {0.f, 0.f, 0.f, 0.f};
    f32x4 acc3 = {0.f, 0.f, 0.f, 0.f};
#pragma unroll
    for (int kk = 0; kk < 8; ++kk) {
        bf16x8 a = *(const bf16x8*)&Hb[m][kk * 32 + quad * 8];
        const unsigned short* wp =
            Wswz + ((size_t)(kk * 8 + wv * 4) * 64 + lane) * 8;
        bf16x8 b0 = *(const bf16x8*)(wp);
        bf16x8 b1 = *(const bf16x8*)(wp + 64 * 8);
        bf16x8 b2 = *(const bf16x8*)(wp + 2 * 64 * 8);
        bf16x8 b3 = *(const bf16x8*)(wp + 3 * 64 * 8);
        acc0 = __builtin_amdgcn_mfma_f32_16x16x32_bf16(a, b0, acc0, 0, 0, 0);
        acc1 = __builtin_amdgcn_mfma_f32_16x16x32_bf16(a, b1, acc1, 0, 0, 0);
        acc2 = __builtin_amdgcn_mfma_f32_16x16x32_bf16(a, b2, acc2, 0, 0, 0);
        acc3 = __builtin_amdgcn_mfma_f32_16x16x32_bf16(a, b3, acc3, 0, 0, 0);
    }
    f32x4 accs[4] = {acc0, acc1, acc2, acc3};
#pragma unroll
    for (int c = 0; c < 4; ++c) {
        int feat = wv * 64 + c * 16 + m;
        float bv = bias[feat];
#pragma unroll
        for (int r = 0; r < 4; ++r) {
            int node = n0 + quad * 4 + r;
            if (node < N)
                out[(size_t)node * 128 + feat] = fmaxf(accs[c][r] + bv, 0.f);
        }
    }
}

static inline size_t align256(size_t x) { return (x + 255) & ~(size_t)255; }

extern "C" void kernel_launch(void* const* d_in, const int* in_sizes, int n_in,
                              void* d_out, int out_size, void* d_ws, size_t ws_size,
                              hipStream_t stream) {
    const float* X    = (const float*)d_in[0];
    const int*   src  = (const int*)d_in[1];
    const int*   dst  = (const int*)d_in[2];
    const float* W    = (const float*)d_in[3];
    const float* bias = (const float*)d_in[4];
    float* out = (float*)d_out;

    const int N = in_sizes[0] / 128;
    const int E = in_sizes[1];
    const int P = (N + PART_SZ - 1) >> PART_SHIFT;   // 391

    // Workspace: cursors[P] | deg[N] | offsets[N] | csr[P*CAPP] | parts | Wswz | [Xb]
    char* base = (char*)d_ws;
    size_t o_cursors = 0;
    size_t o_deg     = o_cursors + align256((size_t)P * 4);
    size_t o_off     = o_deg     + align256((size_t)N * 4);
    size_t o_csr     = o_off     + align256((size_t)N * 4);
    size_t o_parts   = o_csr     + align256((size_t)P * CAPP * 4);
    size_t o_wswz    = o_parts   + align256((size_t)P * CAPP * 8);
    size_t o_xb      = o_wswz    + align256((size_t)256 * 128 * 2);
    size_t need_big  = o_xb + (size_t)N * 128 * 2;

    int* cursors = (int*)(base + o_cursors);
    int* deg     = (int*)(base + o_deg);
    int* offsets = (int*)(base + o_off);
    int* csr     = (int*)(base + o_csr);
    unsigned long long* parts = (unsigned long long*)(base + o_parts);
    unsigned short* Wswz = (unsigned short*)(base + o_wswz);

    const bool big = (ws_size >= need_big);
    unsigned short* Xb = big ? (unsigned short*)(base + o_xb)
                             : (unsigned short*)(base + o_parts); // alias parts

    const int nPart1 = (E + CHUNK - 1) / CHUNK;      // 782
    const int total4 = (N * 128) / 4;
    const int nXw    = (total4 + 255) / 256;         // 12500

    zero_cursors<<<(P + 255) / 256, 256, 0, stream>>>(cursors, P);

    if (big) {
        // fused: partition pass + X/W conversion in one launch
        pre1<<<nPart1 + nXw, 256, 0, stream>>>(
            src, dst, cursors, parts, E, N, P, nPart1, X, Xb, total4, W, Wswz);
        part2<<<P, 256, 0, stream>>>(parts, cursors, csr, offsets, deg, N, P);
    } else {
        pre1<<<nPart1, 256, 0, stream>>>(
            src, dst, cursors, parts, E, N, P, nPart1, X, Xb, total4, W, Wswz);
        part2<<<P, 256, 0, stream>>>(parts, cursors, csr, offsets, deg, N, P);
        // conversion after part2 (Xb aliases parts)
        pre1<<<nXw, 256, 0, stream>>>(
            src, dst, cursors, parts, E, N, P, 0, X, Xb, total4, W, Wswz);
    }

    gather_gemm<<<(N + NODES_PER_BLOCK - 1) / NODES_PER_BLOCK, 128, 0, stream>>>(
        Xb, csr, offsets, deg, Wswz, bias, out, N);
}